// Round 3
// baseline (227.481 us; speedup 1.0000x reference)
//
#include <hip/hip_runtime.h>

#define K_CLUSTERS 512
#define D_FEAT 64
#define ROWS_PER_BLOCK 64
#define THREADS 512

typedef short bf16x8 __attribute__((ext_vector_type(8)));
typedef short bf16x4 __attribute__((ext_vector_type(4)));
typedef float f32x4 __attribute__((ext_vector_type(4)));

__device__ __forceinline__ unsigned short f32_to_bf16(float f) {
  unsigned int u = __float_as_uint(f);
  u += 0x7fffu + ((u >> 16) & 1u);   // RNE
  return (unsigned short)(u >> 16);
}
// truncation (round-to-zero): fine for the HI part of a hi/lo pair — the pair
// error is set by lo's rounding, not hi's. 1 VALU op vs 3.
__device__ __forceinline__ unsigned short f32_to_bf16_trunc(float f) {
  return (unsigned short)(__float_as_uint(f) >> 16);
}
// round-half-up: same 0.5-ulp max error as RNE, 2 VALU ops instead of 4.
__device__ __forceinline__ unsigned short f32_to_bf16_rhu(float f) {
  return (unsigned short)((__float_as_uint(f) + 0x8000u) >> 16);
}
__device__ __forceinline__ float bf16_to_f32(unsigned short h) {
  return __uint_as_float(((unsigned int)h) << 16);
}

// W swizzle: element cx = c ^ ((row&7)<<3). 8-elem chunks keyed on row so the
// Phase-C b128 reads (16 lanes = 16 rows, same 8-elem chunk base) spread over
// all 32 banks at 2 lanes/bank (free); Phase-A b16 scatter writes merge within
// dwords and stay <=2-way.
#define WSWZ(row) ((((unsigned)(row)) & 7u) << 3)

// ---------------- prep: one wave per cluster, lane = feature. Coalesced.
__global__ void kmeans_prep(const float* __restrict__ cent,
                            unsigned short* __restrict__ chi,   // [K][D]
                            unsigned short* __restrict__ clo,   // [K][D]
                            unsigned short* __restrict__ cthi,  // [D][K]
                            unsigned short* __restrict__ ctlo,  // [D][K]
                            float* __restrict__ csqs) {         // [K], 10*log2e*|c|^2
  const int wv = threadIdx.x >> 6;
  const int lane = threadIdx.x & 63;
  const int k = blockIdx.x * 4 + wv;    // grid = 128 blocks -> k in [0,512)
  const int f = lane;
  float v = cent[k * D_FEAT + f];
  unsigned short h = f32_to_bf16_trunc(v);
  float rem = v - bf16_to_f32(h);
  unsigned short l = f32_to_bf16(rem);
  chi[k * D_FEAT + f] = h;
  clo[k * D_FEAT + f] = l;
  cthi[f * K_CLUSTERS + k] = h;
  ctlo[f * K_CLUSTERS + k] = l;
  float s = v * v;
#pragma unroll
  for (int d = 1; d < 64; d <<= 1) s += __shfl_xor(s, d, 64);
  if (lane == 0) csqs[k] = s * 14.42695040888963f;  // 10 * log2(e)
}

// ---------------- main fused kernel: 64 rows/block, 8 waves/block.
// 8 waves x 64KiB W -> LDS/block 67.5KiB -> 2 blocks/CU = 16 waves/CU =
// 4 waves/SIMD, at UNCHANGED per-wave ILP (rt=4 chains) and register budget
// (this structure compiled to 108 VGPR <= the 128 cap). R1's regression
// showed occupancy bought by halving ILP + VGPR loses; this buys it free.
// Phase A: cluster-split (wave owns 64 clusters, all 4 row-tiles), depth-2
// prefetch, weights exp'd + streamed to swizzled LDS (no max pass: logits
// bounded in exp2 domain).
// Phase C: (feat-slice x row-half)-split (wave owns 16 feats x 32 rows),
// W from LDS, depth-2 prefetch; B operands prefetched before the barrier.
__global__ __launch_bounds__(THREADS, 4) void kmeans_main(
    const float* __restrict__ x,
    const unsigned short* __restrict__ chi,
    const unsigned short* __restrict__ clo,
    const unsigned short* __restrict__ cthi,
    const unsigned short* __restrict__ ctlo,
    const float* __restrict__ csqs,
    float* __restrict__ out) {
  // LDS: W [64][512] bf16 (65536 B, swizzled) + redsum [64][8] f32 (2048 B).
  // x staging xh/xl [64][72] (18432 B) aliases head of W (dead after A-frag
  // loads, fenced by barrier 2).
  __shared__ __attribute__((aligned(16))) unsigned char smem[65536 + 2048];
  unsigned short* xh = (unsigned short*)smem;            // [64][72]
  unsigned short* xl = xh + 64 * 72;                     // [64][72]
  unsigned short* W  = (unsigned short*)smem;            // [64][512] swizzled
  float* redsum = (float*)(smem + 65536);                // [64][8]

  const int tid  = threadIdx.x;
  const int wv   = tid >> 6;       // 0..7
  const int lane = tid & 63;
  const int l16  = lane & 15;
  const int quad = lane >> 4;
  const long long rowbase = (long long)blockIdx.x * ROWS_PER_BLOCK;

  // ---- stage x -> xh/xl (coalesced float4 loads, hi=trunc/lo=RNE split) ----
  {
    int r  = tid >> 3;             // 0..63
    int f0 = (tid & 7) * 8;        // 0,8,...,56
    const float4* src4 = (const float4*)(x + (rowbase + r) * D_FEAT + f0);
#pragma unroll
    for (int i = 0; i < 2; ++i) {
      float4 v = src4[i];
      float vv[4] = {v.x, v.y, v.z, v.w};
      bf16x4 hi, lo;
#pragma unroll
      for (int j = 0; j < 4; ++j) {
        unsigned short h = f32_to_bf16_trunc(vv[j]);
        hi[j] = (short)h;
        lo[j] = (short)f32_to_bf16(vv[j] - bf16_to_f32(h));
      }
      *(bf16x4*)(xh + r * 72 + f0 + i * 4) = hi;
      *(bf16x4*)(xl + r * 72 + f0 + i * 4) = lo;
    }
  }
  __syncthreads();   // staging visible

  // ---- A fragments for all 4 row-tiles: A[m=l16][k=quad*8+j], 64 VGPRs ----
  bf16x8 ah[4][2], al[4][2];
#pragma unroll
  for (int rt = 0; rt < 4; ++rt)
#pragma unroll
    for (int ks = 0; ks < 2; ++ks) {
      ah[rt][ks] = *(const bf16x8*)(xh + (rt * 16 + l16) * 72 + ks * 32 + quad * 8);
      al[rt][ks] = *(const bf16x8*)(xl + (rt * 16 + l16) * 72 + ks * 32 + quad * 8);
    }
  __syncthreads();   // xh/xl dead -> W region writable

  // ---- Phase A: wave's 64-cluster slice x 64 rows, depth-2 prefetch ----
  const int cbase = wv * 64;
  const int bko = quad * 8;
  f32x4 srow[4] = {{0.f,0.f,0.f,0.f},{0.f,0.f,0.f,0.f},{0.f,0.f,0.f,0.f},{0.f,0.f,0.f,0.f}};

  bf16x8 pbh0[2], pbh1[2], pbl0[2], pbl1[2];
  float pcs[2];
#pragma unroll
  for (int p = 0; p < 2; ++p) {
    int cl = cbase + p * 16 + l16;
    pbh0[p] = *(const bf16x8*)(chi + cl * 64 + bko);
    pbh1[p] = *(const bf16x8*)(chi + cl * 64 + 32 + bko);
    pbl0[p] = *(const bf16x8*)(clo + cl * 64 + bko);
    pbl1[p] = *(const bf16x8*)(clo + cl * 64 + 32 + bko);
    pcs[p]  = csqs[cl];
  }

#pragma unroll
  for (int t = 0; t < 4; ++t) {
    const int sl = t & 1;
    bf16x8 cbh0 = pbh0[sl], cbh1 = pbh1[sl], cbl0 = pbl0[sl], cbl1 = pbl1[sl];
    float ccs = pcs[sl];
    if (t < 2) {   // prefetch t+2
      int cl = cbase + (t + 2) * 16 + l16;
      pbh0[sl] = *(const bf16x8*)(chi + cl * 64 + bko);
      pbh1[sl] = *(const bf16x8*)(chi + cl * 64 + 32 + bko);
      pbl0[sl] = *(const bf16x8*)(clo + cl * 64 + bko);
      pbl1[sl] = *(const bf16x8*)(clo + cl * 64 + 32 + bko);
      pcs[sl]  = csqs[cl];
    }
    const int c = cbase + t * 16 + l16;
#pragma unroll
    for (int rt = 0; rt < 4; ++rt) {
      f32x4 a = {0.f, 0.f, 0.f, 0.f};
      a = __builtin_amdgcn_mfma_f32_16x16x32_bf16(ah[rt][0], cbh0, a, 0, 0, 0);
      a = __builtin_amdgcn_mfma_f32_16x16x32_bf16(ah[rt][1], cbh1, a, 0, 0, 0);
      a = __builtin_amdgcn_mfma_f32_16x16x32_bf16(ah[rt][0], cbl0, a, 0, 0, 0);
      a = __builtin_amdgcn_mfma_f32_16x16x32_bf16(ah[rt][1], cbl1, a, 0, 0, 0);
      a = __builtin_amdgcn_mfma_f32_16x16x32_bf16(al[rt][0], cbh0, a, 0, 0, 0);
      a = __builtin_amdgcn_mfma_f32_16x16x32_bf16(al[rt][1], cbh1, a, 0, 0, 0);
      // weight = 2^(20*log2e*cross - 10*log2e*|c|^2); row const cancels
#pragma unroll
      for (int r = 0; r < 4; ++r) {
        float e = exp2f(fmaf(28.85390081777927f, a[r], -ccs));
        srow[rt][r] += e;
        int row = rt * 16 + quad * 4 + r;
        W[row * 512 + ((unsigned)c ^ WSWZ(row))] = f32_to_bf16_rhu(e);
      }
    }
  }

  // ---- Phase C B prefetch issued early: hides under reduce + barrier ----
  const int feat = (wv & 3) * 16 + l16;
  const int rtb  = (wv >> 2) << 1;          // 0 or 2
  const unsigned short* cth = cthi + feat * K_CLUSTERS;
  const unsigned short* ctl = ctlo + feat * K_CLUSTERS;
  bf16x8 qbh[2], qbl[2];
#pragma unroll
  for (int p = 0; p < 2; ++p) {
    qbh[p] = *(const bf16x8*)(cth + p * 32 + quad * 8);
    qbl[p] = *(const bf16x8*)(ctl + p * 32 + quad * 8);
  }

  // ---- per-wave partial row sums -> LDS ----
#pragma unroll
  for (int d = 1; d < 16; d <<= 1)
#pragma unroll
    for (int rt = 0; rt < 4; ++rt)
#pragma unroll
      for (int r = 0; r < 4; ++r) srow[rt][r] += __shfl_xor(srow[rt][r], d, 64);
  if (l16 == 0) {
#pragma unroll
    for (int rt = 0; rt < 4; ++rt)
#pragma unroll
      for (int r = 0; r < 4; ++r)
        redsum[(rt * 16 + quad * 4 + r) * 8 + wv] = srow[rt][r];
  }
  __syncthreads();   // W + redsum visible to all waves

  // ---- reciprocal row sums for this wave's rows (broadcast LDS reads) ----
  float inv[2][4];
#pragma unroll
  for (int rt2 = 0; rt2 < 2; ++rt2)
#pragma unroll
    for (int r = 0; r < 4; ++r) {
      const float* rs = redsum + ((rtb + rt2) * 16 + quad * 4 + r) * 8;
      f32x4 s4a = *(const f32x4*)rs;
      f32x4 s4b = *(const f32x4*)(rs + 4);
      inv[rt2][r] = __builtin_amdgcn_rcpf(((s4a[0] + s4a[1]) + (s4a[2] + s4a[3])) +
                                          ((s4b[0] + s4b[1]) + (s4b[2] + s4b[3])));
    }

  // ---- Phase C: wave's 16-feat x 32-row slice, full K=512, depth-2 prefetch ----
  f32x4 oacc[2] = {{0.f,0.f,0.f,0.f},{0.f,0.f,0.f,0.f}};

#pragma unroll
  for (int ks = 0; ks < 16; ++ks) {
    const int sl = ks & 1;
    bf16x8 bh = qbh[sl], bl = qbl[sl];
    if (ks < 14) {   // prefetch ks+2
      qbh[sl] = *(const bf16x8*)(cth + (ks + 2) * 32 + quad * 8);
      qbl[sl] = *(const bf16x8*)(ctl + (ks + 2) * 32 + quad * 8);
    }
    const int ac = ks * 32 + quad * 8;
#pragma unroll
    for (int rt2 = 0; rt2 < 2; ++rt2) {
      int arow = (rtb + rt2) * 16 + l16;
      bf16x8 aw = *(const bf16x8*)(W + arow * 512 + ((unsigned)ac ^ WSWZ(arow)));
      oacc[rt2] = __builtin_amdgcn_mfma_f32_16x16x32_bf16(aw, bh, oacc[rt2], 0, 0, 0);
      oacc[rt2] = __builtin_amdgcn_mfma_f32_16x16x32_bf16(aw, bl, oacc[rt2], 0, 0, 0);
    }
  }

  // ---- epilogue: normalize, store ----
#pragma unroll
  for (int rt2 = 0; rt2 < 2; ++rt2) {
    float* obase = out + (rowbase + (rtb + rt2) * 16) * D_FEAT + feat;
#pragma unroll
    for (int r = 0; r < 4; ++r)
      obase[(quad * 4 + r) * D_FEAT] = oacc[rt2][r] * inv[rt2][r];
  }
}

extern "C" void kernel_launch(void* const* d_in, const int* in_sizes, int n_in,
                              void* d_out, int out_size, void* d_ws, size_t ws_size,
                              hipStream_t stream) {
  const float* x    = (const float*)d_in[0];
  const float* cent = (const float*)d_in[1];
  float* out        = (float*)d_out;

  unsigned short* chi  = (unsigned short*)d_ws;
  unsigned short* clo  = chi  + K_CLUSTERS * D_FEAT;
  unsigned short* cthi = clo  + K_CLUSTERS * D_FEAT;
  unsigned short* ctlo = cthi + K_CLUSTERS * D_FEAT;
  float*          csqs = (float*)(ctlo + K_CLUSTERS * D_FEAT);

  kmeans_prep<<<K_CLUSTERS / 4, 256, 0, stream>>>(
      cent, chi, clo, cthi, ctlo, csqs);

  int nrows = in_sizes[0] / D_FEAT;  // 131072
  kmeans_main<<<nrows / ROWS_PER_BLOCK, THREADS, 0, stream>>>(
      x, chi, clo, cthi, ctlo, csqs, out);
}

// Round 4
// 197.877 us; speedup vs baseline: 1.1496x; 1.1496x over previous
//
#include <hip/hip_runtime.h>

#define K_CLUSTERS 512
#define D_FEAT 64
#define ROWS_PER_BLOCK 64
#define THREADS 512

typedef short bf16x8 __attribute__((ext_vector_type(8)));
typedef short bf16x4 __attribute__((ext_vector_type(4)));
typedef float f32x4 __attribute__((ext_vector_type(4)));

__device__ __forceinline__ unsigned short f32_to_bf16(float f) {
  unsigned int u = __float_as_uint(f);
  u += 0x7fffu + ((u >> 16) & 1u);   // RNE
  return (unsigned short)(u >> 16);
}
// truncation (round-to-zero): fine for the HI part of a hi/lo pair — the pair
// error is set by lo's rounding, not hi's. 1 VALU op vs 3.
__device__ __forceinline__ unsigned short f32_to_bf16_trunc(float f) {
  return (unsigned short)(__float_as_uint(f) >> 16);
}
// round-half-up: same 0.5-ulp max error as RNE, 2 VALU ops instead of 4.
__device__ __forceinline__ unsigned short f32_to_bf16_rhu(float f) {
  return (unsigned short)((__float_as_uint(f) + 0x8000u) >> 16);
}
__device__ __forceinline__ float bf16_to_f32(unsigned short h) {
  return __uint_as_float(((unsigned int)h) << 16);
}

// W swizzle: element cx = c ^ ((row&7)<<3). 8-elem chunks keyed on row so the
// Phase-C b128 reads (16 lanes = 16 rows, same 8-elem chunk base) spread over
// all 32 banks at 2 lanes/bank (free); Phase-A b16 scatter writes merge within
// dwords and stay <=2-way.
#define WSWZ(row) ((((unsigned)(row)) & 7u) << 3)

// ---------------- prep: one wave per cluster, lane = feature. Coalesced.
__global__ void kmeans_prep(const float* __restrict__ cent,
                            unsigned short* __restrict__ chi,   // [K][D]
                            unsigned short* __restrict__ clo,   // [K][D]
                            unsigned short* __restrict__ cthi,  // [D][K]
                            unsigned short* __restrict__ ctlo,  // [D][K]
                            float* __restrict__ csqs) {         // [K], 10*log2e*|c|^2
  const int wv = threadIdx.x >> 6;
  const int lane = threadIdx.x & 63;
  const int k = blockIdx.x * 4 + wv;    // grid = 128 blocks -> k in [0,512)
  const int f = lane;
  float v = cent[k * D_FEAT + f];
  unsigned short h = f32_to_bf16_trunc(v);
  float rem = v - bf16_to_f32(h);
  unsigned short l = f32_to_bf16(rem);
  chi[k * D_FEAT + f] = h;
  clo[k * D_FEAT + f] = l;
  cthi[f * K_CLUSTERS + k] = h;
  ctlo[f * K_CLUSTERS + k] = l;
  float s = v * v;
#pragma unroll
  for (int d = 1; d < 64; d <<= 1) s += __shfl_xor(s, d, 64);
  if (lane == 0) csqs[k] = s * 14.42695040888963f;  // 10 * log2(e)
}

// ---------------- main fused kernel: 64 rows/block, 8 waves/block.
// __launch_bounds__(512, 2): min 2 BLOCKS/CU (HIP 2nd arg behaves as CUDA
// min-blocks here — R3's (512,4) produced a 64-VGPR cap = 8 waves/SIMD and
// ~356 MB of spill traffic). 2 blocks/CU -> VGPR cap 128 >= the ~108 this
// structure needs; LDS 67584 B also gives exactly 2 blocks/CU -> 16 waves/CU
// = 4 waves/SIMD at UNCHANGED per-wave ILP (rt=4 chains). This is the clean
// occupancy-at-constant-ILP experiment R3 was meant to be.
// Phase A: cluster-split (wave owns 64 clusters, all 4 row-tiles), depth-2
// prefetch, weights exp'd + streamed to swizzled LDS (no max pass: logits
// bounded in exp2 domain).
// Phase C: (feat-slice x row-half)-split (wave owns 16 feats x 32 rows),
// W from LDS, depth-2 prefetch; B operands prefetched before the barrier.
__global__ __launch_bounds__(THREADS, 2) void kmeans_main(
    const float* __restrict__ x,
    const unsigned short* __restrict__ chi,
    const unsigned short* __restrict__ clo,
    const unsigned short* __restrict__ cthi,
    const unsigned short* __restrict__ ctlo,
    const float* __restrict__ csqs,
    float* __restrict__ out) {
  // LDS: W [64][512] bf16 (65536 B, swizzled) + redsum [64][8] f32 (2048 B).
  // x staging xh/xl [64][72] (18432 B) aliases head of W (dead after A-frag
  // loads, fenced by barrier 2).
  __shared__ __attribute__((aligned(16))) unsigned char smem[65536 + 2048];
  unsigned short* xh = (unsigned short*)smem;            // [64][72]
  unsigned short* xl = xh + 64 * 72;                     // [64][72]
  unsigned short* W  = (unsigned short*)smem;            // [64][512] swizzled
  float* redsum = (float*)(smem + 65536);                // [64][8]

  const int tid  = threadIdx.x;
  const int wv   = tid >> 6;       // 0..7
  const int lane = tid & 63;
  const int l16  = lane & 15;
  const int quad = lane >> 4;
  const long long rowbase = (long long)blockIdx.x * ROWS_PER_BLOCK;

  // ---- stage x -> xh/xl (coalesced float4 loads, hi=trunc/lo=RNE split) ----
  {
    int r  = tid >> 3;             // 0..63
    int f0 = (tid & 7) * 8;        // 0,8,...,56
    const float4* src4 = (const float4*)(x + (rowbase + r) * D_FEAT + f0);
#pragma unroll
    for (int i = 0; i < 2; ++i) {
      float4 v = src4[i];
      float vv[4] = {v.x, v.y, v.z, v.w};
      bf16x4 hi, lo;
#pragma unroll
      for (int j = 0; j < 4; ++j) {
        unsigned short h = f32_to_bf16_trunc(vv[j]);
        hi[j] = (short)h;
        lo[j] = (short)f32_to_bf16(vv[j] - bf16_to_f32(h));
      }
      *(bf16x4*)(xh + r * 72 + f0 + i * 4) = hi;
      *(bf16x4*)(xl + r * 72 + f0 + i * 4) = lo;
    }
  }
  __syncthreads();   // staging visible

  // ---- A fragments for all 4 row-tiles: A[m=l16][k=quad*8+j], 64 VGPRs ----
  bf16x8 ah[4][2], al[4][2];
#pragma unroll
  for (int rt = 0; rt < 4; ++rt)
#pragma unroll
    for (int ks = 0; ks < 2; ++ks) {
      ah[rt][ks] = *(const bf16x8*)(xh + (rt * 16 + l16) * 72 + ks * 32 + quad * 8);
      al[rt][ks] = *(const bf16x8*)(xl + (rt * 16 + l16) * 72 + ks * 32 + quad * 8);
    }
  __syncthreads();   // xh/xl dead -> W region writable

  // ---- Phase A: wave's 64-cluster slice x 64 rows, depth-2 prefetch ----
  const int cbase = wv * 64;
  const int bko = quad * 8;
  f32x4 srow[4] = {{0.f,0.f,0.f,0.f},{0.f,0.f,0.f,0.f},{0.f,0.f,0.f,0.f},{0.f,0.f,0.f,0.f}};

  bf16x8 pbh0[2], pbh1[2], pbl0[2], pbl1[2];
  float pcs[2];
#pragma unroll
  for (int p = 0; p < 2; ++p) {
    int cl = cbase + p * 16 + l16;
    pbh0[p] = *(const bf16x8*)(chi + cl * 64 + bko);
    pbh1[p] = *(const bf16x8*)(chi + cl * 64 + 32 + bko);
    pbl0[p] = *(const bf16x8*)(clo + cl * 64 + bko);
    pbl1[p] = *(const bf16x8*)(clo + cl * 64 + 32 + bko);
    pcs[p]  = csqs[cl];
  }

#pragma unroll
  for (int t = 0; t < 4; ++t) {
    const int sl = t & 1;
    bf16x8 cbh0 = pbh0[sl], cbh1 = pbh1[sl], cbl0 = pbl0[sl], cbl1 = pbl1[sl];
    float ccs = pcs[sl];
    if (t < 2) {   // prefetch t+2
      int cl = cbase + (t + 2) * 16 + l16;
      pbh0[sl] = *(const bf16x8*)(chi + cl * 64 + bko);
      pbh1[sl] = *(const bf16x8*)(chi + cl * 64 + 32 + bko);
      pbl0[sl] = *(const bf16x8*)(clo + cl * 64 + bko);
      pbl1[sl] = *(const bf16x8*)(clo + cl * 64 + 32 + bko);
      pcs[sl]  = csqs[cl];
    }
    const int c = cbase + t * 16 + l16;
#pragma unroll
    for (int rt = 0; rt < 4; ++rt) {
      f32x4 a = {0.f, 0.f, 0.f, 0.f};
      a = __builtin_amdgcn_mfma_f32_16x16x32_bf16(ah[rt][0], cbh0, a, 0, 0, 0);
      a = __builtin_amdgcn_mfma_f32_16x16x32_bf16(ah[rt][1], cbh1, a, 0, 0, 0);
      a = __builtin_amdgcn_mfma_f32_16x16x32_bf16(ah[rt][0], cbl0, a, 0, 0, 0);
      a = __builtin_amdgcn_mfma_f32_16x16x32_bf16(ah[rt][1], cbl1, a, 0, 0, 0);
      a = __builtin_amdgcn_mfma_f32_16x16x32_bf16(al[rt][0], cbh0, a, 0, 0, 0);
      a = __builtin_amdgcn_mfma_f32_16x16x32_bf16(al[rt][1], cbh1, a, 0, 0, 0);
      // weight = 2^(20*log2e*cross - 10*log2e*|c|^2); row const cancels
#pragma unroll
      for (int r = 0; r < 4; ++r) {
        float e = exp2f(fmaf(28.85390081777927f, a[r], -ccs));
        srow[rt][r] += e;
        int row = rt * 16 + quad * 4 + r;
        W[row * 512 + ((unsigned)c ^ WSWZ(row))] = f32_to_bf16_rhu(e);
      }
    }
  }

  // ---- Phase C B prefetch issued early: hides under reduce + barrier ----
  const int feat = (wv & 3) * 16 + l16;
  const int rtb  = (wv >> 2) << 1;          // 0 or 2
  const unsigned short* cth = cthi + feat * K_CLUSTERS;
  const unsigned short* ctl = ctlo + feat * K_CLUSTERS;
  bf16x8 qbh[2], qbl[2];
#pragma unroll
  for (int p = 0; p < 2; ++p) {
    qbh[p] = *(const bf16x8*)(cth + p * 32 + quad * 8);
    qbl[p] = *(const bf16x8*)(ctl + p * 32 + quad * 8);
  }

  // ---- per-wave partial row sums -> LDS ----
#pragma unroll
  for (int d = 1; d < 16; d <<= 1)
#pragma unroll
    for (int rt = 0; rt < 4; ++rt)
#pragma unroll
      for (int r = 0; r < 4; ++r) srow[rt][r] += __shfl_xor(srow[rt][r], d, 64);
  if (l16 == 0) {
#pragma unroll
    for (int rt = 0; rt < 4; ++rt)
#pragma unroll
      for (int r = 0; r < 4; ++r)
        redsum[(rt * 16 + quad * 4 + r) * 8 + wv] = srow[rt][r];
  }
  __syncthreads();   // W + redsum visible to all waves

  // ---- reciprocal row sums for this wave's rows (broadcast LDS reads) ----
  float inv[2][4];
#pragma unroll
  for (int rt2 = 0; rt2 < 2; ++rt2)
#pragma unroll
    for (int r = 0; r < 4; ++r) {
      const float* rs = redsum + ((rtb + rt2) * 16 + quad * 4 + r) * 8;
      f32x4 s4a = *(const f32x4*)rs;
      f32x4 s4b = *(const f32x4*)(rs + 4);
      inv[rt2][r] = __builtin_amdgcn_rcpf(((s4a[0] + s4a[1]) + (s4a[2] + s4a[3])) +
                                          ((s4b[0] + s4b[1]) + (s4b[2] + s4b[3])));
    }

  // ---- Phase C: wave's 16-feat x 32-row slice, full K=512, depth-2 prefetch ----
  f32x4 oacc[2] = {{0.f,0.f,0.f,0.f},{0.f,0.f,0.f,0.f}};

#pragma unroll
  for (int ks = 0; ks < 16; ++ks) {
    const int sl = ks & 1;
    bf16x8 bh = qbh[sl], bl = qbl[sl];
    if (ks < 14) {   // prefetch ks+2
      qbh[sl] = *(const bf16x8*)(cth + (ks + 2) * 32 + quad * 8);
      qbl[sl] = *(const bf16x8*)(ctl + (ks + 2) * 32 + quad * 8);
    }
    const int ac = ks * 32 + quad * 8;
#pragma unroll
    for (int rt2 = 0; rt2 < 2; ++rt2) {
      int arow = (rtb + rt2) * 16 + l16;
      bf16x8 aw = *(const bf16x8*)(W + arow * 512 + ((unsigned)ac ^ WSWZ(arow)));
      oacc[rt2] = __builtin_amdgcn_mfma_f32_16x16x32_bf16(aw, bh, oacc[rt2], 0, 0, 0);
      oacc[rt2] = __builtin_amdgcn_mfma_f32_16x16x32_bf16(aw, bl, oacc[rt2], 0, 0, 0);
    }
  }

  // ---- epilogue: normalize, store ----
#pragma unroll
  for (int rt2 = 0; rt2 < 2; ++rt2) {
    float* obase = out + (rowbase + (rtb + rt2) * 16) * D_FEAT + feat;
#pragma unroll
    for (int r = 0; r < 4; ++r)
      obase[(quad * 4 + r) * D_FEAT] = oacc[rt2][r] * inv[rt2][r];
  }
}

extern "C" void kernel_launch(void* const* d_in, const int* in_sizes, int n_in,
                              void* d_out, int out_size, void* d_ws, size_t ws_size,
                              hipStream_t stream) {
  const float* x    = (const float*)d_in[0];
  const float* cent = (const float*)d_in[1];
  float* out        = (float*)d_out;

  unsigned short* chi  = (unsigned short*)d_ws;
  unsigned short* clo  = chi  + K_CLUSTERS * D_FEAT;
  unsigned short* cthi = clo  + K_CLUSTERS * D_FEAT;
  unsigned short* ctlo = cthi + K_CLUSTERS * D_FEAT;
  float*          csqs = (float*)(ctlo + K_CLUSTERS * D_FEAT);

  kmeans_prep<<<K_CLUSTERS / 4, 256, 0, stream>>>(
      cent, chi, clo, cthi, ctlo, csqs);

  int nrows = in_sizes[0] / D_FEAT;  // 131072
  kmeans_main<<<nrows / ROWS_PER_BLOCK, THREADS, 0, stream>>>(
      x, chi, clo, cthi, ctlo, csqs, out);
}

// Round 5
// 140.243 us; speedup vs baseline: 1.6220x; 1.4110x over previous
//
#include <hip/hip_runtime.h>

#define K_CLUSTERS 512
#define D_FEAT 64
#define ROWS_PER_BLOCK 64
#define THREADS 256

typedef short bf16x8 __attribute__((ext_vector_type(8)));
typedef short bf16x4 __attribute__((ext_vector_type(4)));
typedef float f32x4 __attribute__((ext_vector_type(4)));

__device__ __forceinline__ unsigned short f32_to_bf16(float f) {
  unsigned int u = __float_as_uint(f);
  u += 0x7fffu + ((u >> 16) & 1u);   // RNE
  return (unsigned short)(u >> 16);
}
// truncation (round-to-zero): fine for the HI part of a hi/lo pair — the pair
// error is set by lo's rounding, not hi's. 1 VALU op vs 3.
__device__ __forceinline__ unsigned short f32_to_bf16_trunc(float f) {
  return (unsigned short)(__float_as_uint(f) >> 16);
}
// round-half-up: same 0.5-ulp max error as RNE, 2 VALU ops instead of 4.
__device__ __forceinline__ unsigned short f32_to_bf16_rhu(float f) {
  return (unsigned short)((__float_as_uint(f) + 0x8000u) >> 16);
}
__device__ __forceinline__ float bf16_to_f32(unsigned short h) {
  return __uint_as_float(((unsigned int)h) << 16);
}

// W swizzle: element cx = c ^ ((row&7)<<3). 8-elem chunks keyed on row so the
// Phase-C b128 reads (16 lanes = 16 rows, same 8-elem chunk base) spread over
// all 32 banks at 2 lanes/bank (free); Phase-A b16 scatter writes merge within
// dwords and stay <=2-way.
#define WSWZ(row) ((((unsigned)(row)) & 7u) << 3)

// ---------------- prep: one wave per cluster, lane = feature. Coalesced.
__global__ void kmeans_prep(const float* __restrict__ cent,
                            unsigned short* __restrict__ chi,   // [K][D]
                            unsigned short* __restrict__ clo,   // [K][D]
                            unsigned short* __restrict__ cthi,  // [D][K]
                            unsigned short* __restrict__ ctlo,  // [D][K]
                            float* __restrict__ csqs) {         // [K], 10*log2e*|c|^2
  const int wv = threadIdx.x >> 6;
  const int lane = threadIdx.x & 63;
  const int k = blockIdx.x * 4 + wv;    // grid = 128 blocks -> k in [0,512)
  const int f = lane;
  float v = cent[k * D_FEAT + f];
  unsigned short h = f32_to_bf16_trunc(v);
  float rem = v - bf16_to_f32(h);
  unsigned short l = f32_to_bf16(rem);
  chi[k * D_FEAT + f] = h;
  clo[k * D_FEAT + f] = l;
  cthi[f * K_CLUSTERS + k] = h;
  ctlo[f * K_CLUSTERS + k] = l;
  float s = v * v;
#pragma unroll
  for (int d = 1; d < 64; d <<= 1) s += __shfl_xor(s, d, 64);
  if (lane == 0) csqs[k] = s * 14.42695040888963f;  // 10 * log2(e)
}

// ---------------- main fused kernel: 64 rows/block, 4 waves (R0 skeleton).
// Evidence R0/R2/R4: perf tracks per-wave ILP, not occupancy. This round:
// (1) row sums via MFMA against an all-ones B-frag (osum) — removes srow
//     VALU adds, the shfl_xor reduction, and the redsum LDS round-trip; the
//     osum D-layout aligns exactly with oacc rows, so inv needs no shuffles.
// (2) chain-split accumulators: Phase A a_hi||a_lo (8 chains), Phase C
//     oh||ol||osum (12 chains) — more independent MFMA streams per wave.
// (3) launch_bounds(256,2): occupancy is LDS-capped at 2 blocks/CU; give the
//     allocator room (R3's (512,4) spill disaster: 356 MB scratch traffic).
__global__ __launch_bounds__(THREADS, 2) void kmeans_main(
    const float* __restrict__ x,
    const unsigned short* __restrict__ chi,
    const unsigned short* __restrict__ clo,
    const unsigned short* __restrict__ cthi,
    const unsigned short* __restrict__ ctlo,
    const float* __restrict__ csqs,
    float* __restrict__ out) {
  // LDS: W [64][512] bf16 (65536 B, swizzled). x staging xh/xl [64][72]
  // (18432 B) aliases head of W (dead after A-frag loads, fenced by barrier 2).
  __shared__ __attribute__((aligned(16))) unsigned char smem[65536];
  unsigned short* xh = (unsigned short*)smem;            // [64][72]
  unsigned short* xl = xh + 64 * 72;                     // [64][72]
  unsigned short* W  = (unsigned short*)smem;            // [64][512] swizzled

  const int tid  = threadIdx.x;
  const int wv   = tid >> 6;
  const int lane = tid & 63;
  const int l16  = lane & 15;
  const int quad = lane >> 4;
  const long long rowbase = (long long)blockIdx.x * ROWS_PER_BLOCK;

  // ---- stage x -> xh/xl (coalesced float4 loads, hi=trunc/lo=RNE split) ----
  {
    int r  = tid >> 2;             // 0..63
    int f0 = (tid & 3) * 16;       // 0,16,32,48
    const float4* src4 = (const float4*)(x + (rowbase + r) * D_FEAT + f0);
#pragma unroll
    for (int i = 0; i < 4; ++i) {
      float4 v = src4[i];
      float vv[4] = {v.x, v.y, v.z, v.w};
      bf16x4 hi, lo;
#pragma unroll
      for (int j = 0; j < 4; ++j) {
        unsigned short h = f32_to_bf16_trunc(vv[j]);
        hi[j] = (short)h;
        lo[j] = (short)f32_to_bf16(vv[j] - bf16_to_f32(h));
      }
      *(bf16x4*)(xh + r * 72 + f0 + i * 4) = hi;
      *(bf16x4*)(xl + r * 72 + f0 + i * 4) = lo;
    }
  }
  __syncthreads();   // staging visible

  // ---- A fragments for all 4 row-tiles: A[m=l16][k=quad*8+j], 64 VGPRs ----
  bf16x8 ah[4][2], al[4][2];
#pragma unroll
  for (int rt = 0; rt < 4; ++rt)
#pragma unroll
    for (int ks = 0; ks < 2; ++ks) {
      ah[rt][ks] = *(const bf16x8*)(xh + (rt * 16 + l16) * 72 + ks * 32 + quad * 8);
      al[rt][ks] = *(const bf16x8*)(xl + (rt * 16 + l16) * 72 + ks * 32 + quad * 8);
    }
  __syncthreads();   // xh/xl dead -> W region writable

  // ---- Phase A: wave's 128-cluster slice x 64 rows, depth-2 prefetch ----
  const int cbase = wv * 128;
  const int bko = quad * 8;

  bf16x8 pbh0[2], pbh1[2], pbl0[2], pbl1[2];
  float pcs[2];
#pragma unroll
  for (int p = 0; p < 2; ++p) {
    int cl = cbase + p * 16 + l16;
    pbh0[p] = *(const bf16x8*)(chi + cl * 64 + bko);
    pbh1[p] = *(const bf16x8*)(chi + cl * 64 + 32 + bko);
    pbl0[p] = *(const bf16x8*)(clo + cl * 64 + bko);
    pbl1[p] = *(const bf16x8*)(clo + cl * 64 + 32 + bko);
    pcs[p]  = csqs[cl];
  }

#pragma unroll
  for (int t = 0; t < 8; ++t) {
    const int sl = t & 1;
    bf16x8 cbh0 = pbh0[sl], cbh1 = pbh1[sl], cbl0 = pbl0[sl], cbl1 = pbl1[sl];
    float ccs = pcs[sl];
    if (t < 6) {   // prefetch t+2
      int cl = cbase + (t + 2) * 16 + l16;
      pbh0[sl] = *(const bf16x8*)(chi + cl * 64 + bko);
      pbh1[sl] = *(const bf16x8*)(chi + cl * 64 + 32 + bko);
      pbl0[sl] = *(const bf16x8*)(clo + cl * 64 + bko);
      pbl1[sl] = *(const bf16x8*)(clo + cl * 64 + 32 + bko);
      pcs[sl]  = csqs[cl];
    }
    const int c = cbase + t * 16 + l16;
#pragma unroll
    for (int rt = 0; rt < 4; ++rt) {
      // split accumulators: a_hi (4-chain) || a_lo (2-chain)
      f32x4 a_hi = {0.f, 0.f, 0.f, 0.f};
      f32x4 a_lo = {0.f, 0.f, 0.f, 0.f};
      a_hi = __builtin_amdgcn_mfma_f32_16x16x32_bf16(ah[rt][0], cbh0, a_hi, 0, 0, 0);
      a_lo = __builtin_amdgcn_mfma_f32_16x16x32_bf16(al[rt][0], cbh0, a_lo, 0, 0, 0);
      a_hi = __builtin_amdgcn_mfma_f32_16x16x32_bf16(ah[rt][1], cbh1, a_hi, 0, 0, 0);
      a_lo = __builtin_amdgcn_mfma_f32_16x16x32_bf16(al[rt][1], cbh1, a_lo, 0, 0, 0);
      a_hi = __builtin_amdgcn_mfma_f32_16x16x32_bf16(ah[rt][0], cbl0, a_hi, 0, 0, 0);
      a_hi = __builtin_amdgcn_mfma_f32_16x16x32_bf16(ah[rt][1], cbl1, a_hi, 0, 0, 0);
      f32x4 a = a_hi + a_lo;
      // weight = 2^(20*log2e*cross - 10*log2e*|c|^2); row const cancels
#pragma unroll
      for (int r = 0; r < 4; ++r) {
        float e = exp2f(fmaf(28.85390081777927f, a[r], -ccs));
        int row = rt * 16 + quad * 4 + r;
        W[row * 512 + ((unsigned)c ^ WSWZ(row))] = f32_to_bf16_rhu(e);
      }
    }
  }

  // ---- Phase C B prefetch issued early: hides under the barrier ----
  const int feat = wv * 16 + l16;
  const unsigned short* cth = cthi + feat * K_CLUSTERS;
  const unsigned short* ctl = ctlo + feat * K_CLUSTERS;
  bf16x8 qbh[2], qbl[2];
#pragma unroll
  for (int p = 0; p < 2; ++p) {
    qbh[p] = *(const bf16x8*)(cth + p * 32 + quad * 8);
    qbl[p] = *(const bf16x8*)(ctl + p * 32 + quad * 8);
  }
  // all-ones bf16 B-frag for MFMA row sums
  bf16x8 ones;
#pragma unroll
  for (int j = 0; j < 8; ++j) ones[j] = (short)0x3F80;

  __syncthreads();   // W visible to all waves

  // ---- Phase C: wave's 16-feature slice, full K=512, depth-2 prefetch.
  // 12 independent chains: oh[4] (W*Chi), ol[4] (W*Clo), os[4] (row sums).
  f32x4 oh[4] = {{0.f,0.f,0.f,0.f},{0.f,0.f,0.f,0.f},{0.f,0.f,0.f,0.f},{0.f,0.f,0.f,0.f}};
  f32x4 ol[4] = {{0.f,0.f,0.f,0.f},{0.f,0.f,0.f,0.f},{0.f,0.f,0.f,0.f},{0.f,0.f,0.f,0.f}};
  f32x4 os[4] = {{0.f,0.f,0.f,0.f},{0.f,0.f,0.f,0.f},{0.f,0.f,0.f,0.f},{0.f,0.f,0.f,0.f}};

#pragma unroll
  for (int ks = 0; ks < 16; ++ks) {
    const int sl = ks & 1;
    bf16x8 bh = qbh[sl], bl = qbl[sl];
    if (ks < 14) {   // prefetch ks+2
      qbh[sl] = *(const bf16x8*)(cth + (ks + 2) * 32 + quad * 8);
      qbl[sl] = *(const bf16x8*)(ctl + (ks + 2) * 32 + quad * 8);
    }
    const int ac = ks * 32 + quad * 8;
#pragma unroll
    for (int rt = 0; rt < 4; ++rt) {
      int arow = rt * 16 + l16;
      bf16x8 aw = *(const bf16x8*)(W + arow * 512 + ((unsigned)ac ^ WSWZ(arow)));
      oh[rt] = __builtin_amdgcn_mfma_f32_16x16x32_bf16(aw, bh, oh[rt], 0, 0, 0);
      ol[rt] = __builtin_amdgcn_mfma_f32_16x16x32_bf16(aw, bl, ol[rt], 0, 0, 0);
      os[rt] = __builtin_amdgcn_mfma_f32_16x16x32_bf16(aw, ones, os[rt], 0, 0, 0);
    }
  }

  // ---- epilogue: normalize by MFMA row sums (layout-aligned, no shuffles) ----
#pragma unroll
  for (int rt = 0; rt < 4; ++rt) {
    float* obase = out + (rowbase + rt * 16) * D_FEAT + feat;
#pragma unroll
    for (int r = 0; r < 4; ++r) {
      float val = (oh[rt][r] + ol[rt][r]) * __builtin_amdgcn_rcpf(os[rt][r]);
      obase[(quad * 4 + r) * D_FEAT] = val;
    }
  }
}

extern "C" void kernel_launch(void* const* d_in, const int* in_sizes, int n_in,
                              void* d_out, int out_size, void* d_ws, size_t ws_size,
                              hipStream_t stream) {
  const float* x    = (const float*)d_in[0];
  const float* cent = (const float*)d_in[1];
  float* out        = (float*)d_out;

  unsigned short* chi  = (unsigned short*)d_ws;
  unsigned short* clo  = chi  + K_CLUSTERS * D_FEAT;
  unsigned short* cthi = clo  + K_CLUSTERS * D_FEAT;
  unsigned short* ctlo = cthi + K_CLUSTERS * D_FEAT;
  float*          csqs = (float*)(ctlo + K_CLUSTERS * D_FEAT);

  kmeans_prep<<<K_CLUSTERS / 4, 256, 0, stream>>>(
      cent, chi, clo, cthi, ctlo, csqs);

  int nrows = in_sizes[0] / D_FEAT;  // 131072
  kmeans_main<<<nrows / ROWS_PER_BLOCK, THREADS, 0, stream>>>(
      x, chi, clo, cthi, ctlo, csqs, out);
}

// Round 6
// 138.729 us; speedup vs baseline: 1.6398x; 1.0109x over previous
//
#include <hip/hip_runtime.h>

#define K_CLUSTERS 512
#define D_FEAT 64
#define ROWS_PER_BLOCK 64
#define THREADS 256

typedef short bf16x8 __attribute__((ext_vector_type(8)));
typedef short bf16x4 __attribute__((ext_vector_type(4)));
typedef float f32x4 __attribute__((ext_vector_type(4)));

__device__ __forceinline__ unsigned short f32_to_bf16(float f) {
  unsigned int u = __float_as_uint(f);
  u += 0x7fffu + ((u >> 16) & 1u);   // RNE
  return (unsigned short)(u >> 16);
}
// truncation (round-to-zero): fine for the HI part of a hi/lo pair — the pair
// error is set by lo's rounding, not hi's. 1 VALU op vs 3.
__device__ __forceinline__ unsigned short f32_to_bf16_trunc(float f) {
  return (unsigned short)(__float_as_uint(f) >> 16);
}
// round-half-up: same 0.5-ulp max error as RNE, 2 VALU ops instead of 4.
__device__ __forceinline__ unsigned short f32_to_bf16_rhu(float f) {
  return (unsigned short)((__float_as_uint(f) + 0x8000u) >> 16);
}
__device__ __forceinline__ float bf16_to_f32(unsigned short h) {
  return __uint_as_float(((unsigned int)h) << 16);
}

// W swizzle: element cx = c ^ ((row&7)<<3). 8-elem chunks keyed on row so the
// Phase-C b128 reads (16 lanes = 16 rows, same 8-elem chunk base) spread over
// all 32 banks at 2 lanes/bank (free); Phase-A b16 scatter writes merge within
// dwords and stay <=2-way.
#define WSWZ(row) ((((unsigned)(row)) & 7u) << 3)

// ---------------- prep: one wave per cluster, lane = feature. Coalesced.
__global__ void kmeans_prep(const float* __restrict__ cent,
                            unsigned short* __restrict__ chi,   // [K][D]
                            unsigned short* __restrict__ clo,   // [K][D]
                            unsigned short* __restrict__ cthi,  // [D][K]
                            unsigned short* __restrict__ ctlo,  // [D][K]
                            float* __restrict__ csqs) {         // [K], 10*log2e*|c|^2
  const int wv = threadIdx.x >> 6;
  const int lane = threadIdx.x & 63;
  const int k = blockIdx.x * 4 + wv;    // grid = 128 blocks -> k in [0,512)
  const int f = lane;
  float v = cent[k * D_FEAT + f];
  unsigned short h = f32_to_bf16_trunc(v);
  float rem = v - bf16_to_f32(h);
  unsigned short l = f32_to_bf16(rem);
  chi[k * D_FEAT + f] = h;
  clo[k * D_FEAT + f] = l;
  cthi[f * K_CLUSTERS + k] = h;
  ctlo[f * K_CLUSTERS + k] = l;
  float s = v * v;
#pragma unroll
  for (int d = 1; d < 64; d <<= 1) s += __shfl_xor(s, d, 64);
  if (lane == 0) csqs[k] = s * 14.42695040888963f;  // 10 * log2(e)
}

// ---------------- main fused kernel: 64 rows/block, 4 waves (R0 skeleton).
// Cross-round evidence (R0/R2/R4/R5): time tracks per-step latency coverage,
// not occupancy and not pipe-busy totals. Phase C's depth-2 B prefetch gap
// (~2 x 140 cyc) sits AT the L2 latency -> chronic stall; halving per-step
// compute (R2/R4) made it 65% worse. This round covers the latency:
// (1) Phase-C global B prefetch depth 4 (gap ~550 cyc >> L2 ~250).
// (2) all 4 aw ds_read_b128 batched per ks before the 12 MFMAs (LDS latency
//     exposed once per step, not 4x).
// (3) first 4 B slots issued before the W barrier.
// Row sums stay MFMA-based (R5: ones-B-frag, layout-aligned with oacc).
__global__ __launch_bounds__(THREADS, 2) void kmeans_main(
    const float* __restrict__ x,
    const unsigned short* __restrict__ chi,
    const unsigned short* __restrict__ clo,
    const unsigned short* __restrict__ cthi,
    const unsigned short* __restrict__ ctlo,
    const float* __restrict__ csqs,
    float* __restrict__ out) {
  // LDS: W [64][512] bf16 (65536 B, swizzled). x staging xh/xl [64][72]
  // (18432 B) aliases head of W (dead after A-frag loads, fenced by barrier 2).
  __shared__ __attribute__((aligned(16))) unsigned char smem[65536];
  unsigned short* xh = (unsigned short*)smem;            // [64][72]
  unsigned short* xl = xh + 64 * 72;                     // [64][72]
  unsigned short* W  = (unsigned short*)smem;            // [64][512] swizzled

  const int tid  = threadIdx.x;
  const int wv   = tid >> 6;
  const int lane = tid & 63;
  const int l16  = lane & 15;
  const int quad = lane >> 4;
  const long long rowbase = (long long)blockIdx.x * ROWS_PER_BLOCK;

  // ---- stage x -> xh/xl (coalesced float4 loads, hi=trunc/lo=RNE split) ----
  {
    int r  = tid >> 2;             // 0..63
    int f0 = (tid & 3) * 16;       // 0,16,32,48
    const float4* src4 = (const float4*)(x + (rowbase + r) * D_FEAT + f0);
#pragma unroll
    for (int i = 0; i < 4; ++i) {
      float4 v = src4[i];
      float vv[4] = {v.x, v.y, v.z, v.w};
      bf16x4 hi, lo;
#pragma unroll
      for (int j = 0; j < 4; ++j) {
        unsigned short h = f32_to_bf16_trunc(vv[j]);
        hi[j] = (short)h;
        lo[j] = (short)f32_to_bf16(vv[j] - bf16_to_f32(h));
      }
      *(bf16x4*)(xh + r * 72 + f0 + i * 4) = hi;
      *(bf16x4*)(xl + r * 72 + f0 + i * 4) = lo;
    }
  }
  __syncthreads();   // staging visible

  // ---- A fragments for all 4 row-tiles: A[m=l16][k=quad*8+j], 64 VGPRs ----
  bf16x8 ah[4][2], al[4][2];
#pragma unroll
  for (int rt = 0; rt < 4; ++rt)
#pragma unroll
    for (int ks = 0; ks < 2; ++ks) {
      ah[rt][ks] = *(const bf16x8*)(xh + (rt * 16 + l16) * 72 + ks * 32 + quad * 8);
      al[rt][ks] = *(const bf16x8*)(xl + (rt * 16 + l16) * 72 + ks * 32 + quad * 8);
    }
  __syncthreads();   // xh/xl dead -> W region writable

  // ---- Phase A: wave's 128-cluster slice x 64 rows, depth-2 prefetch ----
  const int cbase = wv * 128;
  const int bko = quad * 8;

  bf16x8 pbh0[2], pbh1[2], pbl0[2], pbl1[2];
  float pcs[2];
#pragma unroll
  for (int p = 0; p < 2; ++p) {
    int cl = cbase + p * 16 + l16;
    pbh0[p] = *(const bf16x8*)(chi + cl * 64 + bko);
    pbh1[p] = *(const bf16x8*)(chi + cl * 64 + 32 + bko);
    pbl0[p] = *(const bf16x8*)(clo + cl * 64 + bko);
    pbl1[p] = *(const bf16x8*)(clo + cl * 64 + 32 + bko);
    pcs[p]  = csqs[cl];
  }

#pragma unroll
  for (int t = 0; t < 8; ++t) {
    const int sl = t & 1;
    bf16x8 cbh0 = pbh0[sl], cbh1 = pbh1[sl], cbl0 = pbl0[sl], cbl1 = pbl1[sl];
    float ccs = pcs[sl];
    if (t < 6) {   // prefetch t+2
      int cl = cbase + (t + 2) * 16 + l16;
      pbh0[sl] = *(const bf16x8*)(chi + cl * 64 + bko);
      pbh1[sl] = *(const bf16x8*)(chi + cl * 64 + 32 + bko);
      pbl0[sl] = *(const bf16x8*)(clo + cl * 64 + bko);
      pbl1[sl] = *(const bf16x8*)(clo + cl * 64 + 32 + bko);
      pcs[sl]  = csqs[cl];
    }
    const int c = cbase + t * 16 + l16;
#pragma unroll
    for (int rt = 0; rt < 4; ++rt) {
      // split accumulators: a_hi (4-chain) || a_lo (2-chain)
      f32x4 a_hi = {0.f, 0.f, 0.f, 0.f};
      f32x4 a_lo = {0.f, 0.f, 0.f, 0.f};
      a_hi = __builtin_amdgcn_mfma_f32_16x16x32_bf16(ah[rt][0], cbh0, a_hi, 0, 0, 0);
      a_lo = __builtin_amdgcn_mfma_f32_16x16x32_bf16(al[rt][0], cbh0, a_lo, 0, 0, 0);
      a_hi = __builtin_amdgcn_mfma_f32_16x16x32_bf16(ah[rt][1], cbh1, a_hi, 0, 0, 0);
      a_lo = __builtin_amdgcn_mfma_f32_16x16x32_bf16(al[rt][1], cbh1, a_lo, 0, 0, 0);
      a_hi = __builtin_amdgcn_mfma_f32_16x16x32_bf16(ah[rt][0], cbl0, a_hi, 0, 0, 0);
      a_hi = __builtin_amdgcn_mfma_f32_16x16x32_bf16(ah[rt][1], cbl1, a_hi, 0, 0, 0);
      f32x4 a = a_hi + a_lo;
      // weight = 2^(20*log2e*cross - 10*log2e*|c|^2); row const cancels
#pragma unroll
      for (int r = 0; r < 4; ++r) {
        float e = exp2f(fmaf(28.85390081777927f, a[r], -ccs));
        int row = rt * 16 + quad * 4 + r;
        W[row * 512 + ((unsigned)c ^ WSWZ(row))] = f32_to_bf16_rhu(e);
      }
    }
  }

  // ---- Phase C B prefetch, depth 4, first slots issued before the barrier ----
  const int feat = wv * 16 + l16;
  const unsigned short* cth = cthi + feat * K_CLUSTERS;
  const unsigned short* ctl = ctlo + feat * K_CLUSTERS;
  bf16x8 qbh[4], qbl[4];
#pragma unroll
  for (int p = 0; p < 4; ++p) {
    qbh[p] = *(const bf16x8*)(cth + p * 32 + quad * 8);
    qbl[p] = *(const bf16x8*)(ctl + p * 32 + quad * 8);
  }
  // all-ones bf16 B-frag for MFMA row sums
  bf16x8 ones;
#pragma unroll
  for (int j = 0; j < 8; ++j) ones[j] = (short)0x3F80;

  __syncthreads();   // W visible to all waves

  // ---- Phase C: wave's 16-feature slice, full K=512, depth-4 prefetch.
  // 12 independent chains: oh[4] (W*Chi), ol[4] (W*Clo), os[4] (row sums).
  f32x4 oh[4] = {{0.f,0.f,0.f,0.f},{0.f,0.f,0.f,0.f},{0.f,0.f,0.f,0.f},{0.f,0.f,0.f,0.f}};
  f32x4 ol[4] = {{0.f,0.f,0.f,0.f},{0.f,0.f,0.f,0.f},{0.f,0.f,0.f,0.f},{0.f,0.f,0.f,0.f}};
  f32x4 os[4] = {{0.f,0.f,0.f,0.f},{0.f,0.f,0.f,0.f},{0.f,0.f,0.f,0.f},{0.f,0.f,0.f,0.f}};

#pragma unroll
  for (int ks = 0; ks < 16; ++ks) {
    const int sl = ks & 3;
    bf16x8 bh = qbh[sl], bl = qbl[sl];
    if (ks < 12) {   // prefetch ks+4
      qbh[sl] = *(const bf16x8*)(cth + (ks + 4) * 32 + quad * 8);
      qbl[sl] = *(const bf16x8*)(ctl + (ks + 4) * 32 + quad * 8);
    }
    const int ac = ks * 32 + quad * 8;
    // batch the 4 W reads so ds_read latency is exposed once per ks
    bf16x8 aw[4];
#pragma unroll
    for (int rt = 0; rt < 4; ++rt) {
      int arow = rt * 16 + l16;
      aw[rt] = *(const bf16x8*)(W + arow * 512 + ((unsigned)ac ^ WSWZ(arow)));
    }
#pragma unroll
    for (int rt = 0; rt < 4; ++rt) {
      oh[rt] = __builtin_amdgcn_mfma_f32_16x16x32_bf16(aw[rt], bh, oh[rt], 0, 0, 0);
      ol[rt] = __builtin_amdgcn_mfma_f32_16x16x32_bf16(aw[rt], bl, ol[rt], 0, 0, 0);
      os[rt] = __builtin_amdgcn_mfma_f32_16x16x32_bf16(aw[rt], ones, os[rt], 0, 0, 0);
    }
  }

  // ---- epilogue: normalize by MFMA row sums (layout-aligned, no shuffles) ----
#pragma unroll
  for (int rt = 0; rt < 4; ++rt) {
    float* obase = out + (rowbase + rt * 16) * D_FEAT + feat;
#pragma unroll
    for (int r = 0; r < 4; ++r) {
      float val = (oh[rt][r] + ol[rt][r]) * __builtin_amdgcn_rcpf(os[rt][r]);
      obase[(quad * 4 + r) * D_FEAT] = val;
    }
  }
}

extern "C" void kernel_launch(void* const* d_in, const int* in_sizes, int n_in,
                              void* d_out, int out_size, void* d_ws, size_t ws_size,
                              hipStream_t stream) {
  const float* x    = (const float*)d_in[0];
  const float* cent = (const float*)d_in[1];
  float* out        = (float*)d_out;

  unsigned short* chi  = (unsigned short*)d_ws;
  unsigned short* clo  = chi  + K_CLUSTERS * D_FEAT;
  unsigned short* cthi = clo  + K_CLUSTERS * D_FEAT;
  unsigned short* ctlo = cthi + K_CLUSTERS * D_FEAT;
  float*          csqs = (float*)(ctlo + K_CLUSTERS * D_FEAT);

  kmeans_prep<<<K_CLUSTERS / 4, 256, 0, stream>>>(
      cent, chi, clo, cthi, ctlo, csqs);

  int nrows = in_sizes[0] / D_FEAT;  // 131072
  kmeans_main<<<nrows / ROWS_PER_BLOCK, THREADS, 0, stream>>>(
      x, chi, clo, cthi, ctlo, csqs, out);
}